// Round 2
// baseline (109.693 us; speedup 1.0000x reference)
//
#include <hip/hip_runtime.h>
#include <stdint.h>

// SampleChamfer: out = sum_i min_k ||pa_i - pb_k||^2
// pa_i = a[:, a_idx[i]], pb_k = b[:, b_idx[k]], fp32 scalar out.
//
// d = sq_a[i] + (sq_b[k] - 2*dot(pb_k, pa_i)); min over k; sum over i.
//
// 3-kernel plan, NO memsets, NO atomics (nothing reads uninitialized memory):
//  A: grid (a_chunks x b_chunks); each block: 64 b-points in LDS as
//     (-2bx,-2by,-2bz,||b||^2), 2048 a-points (8/thread in registers);
//     writes partial min to pmin[bc*n + i]  (plain store).
//  B: per a-point: min over the 128 b-chunk partials + ||a||^2, block-sum,
//     writes 32 block partials to psum[].
//  C: one 64-thread block sums the 32 partials, stores d_out (plain store).

#define BLOCK   256
#define NPTS_A  8     // a-points per thread (register tile)
#define BPTS    64    // b-points per block (LDS tile) -> 128 b-chunks, 512 blocks

__global__ __launch_bounds__(BLOCK)
void chamfer_min_kernel(const float* __restrict__ a,
                        const float* __restrict__ b,
                        const int* __restrict__ a_idx,
                        const int* __restrict__ b_idx,
                        float* __restrict__ pmin,
                        int N, int n, int a_chunks) {
    __shared__ float4 tile[BPTS];
    const int bid = blockIdx.x;
    const int ac  = bid % a_chunks;   // which a-chunk of BLOCK*NPTS_A points
    const int bc  = bid / a_chunks;   // which b-chunk of BPTS points
    const int tid = threadIdx.x;

    if (tid < BPTS) {
        int j  = bc * BPTS + tid;
        int bi = b_idx[j];
        float bx = b[bi], by = b[N + bi], bz = b[2 * N + bi];
        tile[tid] = make_float4(-2.f * bx, -2.f * by, -2.f * bz,
                                bx * bx + by * by + bz * bz);
    }
    __syncthreads();

    float ax[NPTS_A], ay[NPTS_A], az[NPTS_A], mn[NPTS_A];
#pragma unroll
    for (int m = 0; m < NPTS_A; ++m) {
        int i = ac * (BLOCK * NPTS_A) + m * BLOCK + tid;  // coalesced
        int ai = a_idx[i];
        ax[m] = a[ai]; ay[m] = a[N + ai]; az[m] = a[2 * N + ai];
        mn[m] = 3.4e38f;
    }

    // 1 broadcast ds_read_b128 per k serves 8 a-points x 4 VALU ops.
    // unroll 4 -> multiple outstanding lgkm loads at 2 waves/SIMD.
#pragma unroll 4
    for (int k = 0; k < BPTS; ++k) {
        float4 t = tile[k];
#pragma unroll
        for (int m = 0; m < NPTS_A; ++m) {
            float c = fmaf(t.x, ax[m], fmaf(t.y, ay[m], fmaf(t.z, az[m], t.w)));
            mn[m] = fminf(mn[m], c);
        }
    }

#pragma unroll
    for (int m = 0; m < NPTS_A; ++m) {
        int i = ac * (BLOCK * NPTS_A) + m * BLOCK + tid;
        pmin[(size_t)bc * n + i] = mn[m];   // plain coalesced store
    }
}

__global__ __launch_bounds__(BLOCK)
void chamfer_colmin_sum_kernel(const float* __restrict__ a,
                               const int* __restrict__ a_idx,
                               const float* __restrict__ pmin,
                               float* __restrict__ psum,
                               int N, int n, int b_chunks) {
    __shared__ float wsum[BLOCK / 64];
    const int tid = threadIdx.x;
    const int i = blockIdx.x * BLOCK + tid;

    float v = 3.4e38f;
    for (int j = 0; j < b_chunks; ++j)         // coalesced: stride n across j
        v = fminf(v, pmin[(size_t)j * n + i]);

    int ai = a_idx[i];
    float x = a[ai], y = a[N + ai], z = a[2 * N + ai];
    v += x * x + y * y + z * z;

#pragma unroll
    for (int off = 32; off > 0; off >>= 1)
        v += __shfl_down(v, off, 64);
    if ((tid & 63) == 0) wsum[tid >> 6] = v;
    __syncthreads();
    if (tid == 0) {
        float s = 0.f;
#pragma unroll
        for (int w = 0; w < BLOCK / 64; ++w) s += wsum[w];
        psum[blockIdx.x] = s;
    }
}

__global__ __launch_bounds__(64)
void chamfer_final_kernel(const float* __restrict__ psum,
                          float* __restrict__ out, int nblocks) {
    const int tid = threadIdx.x;
    float v = (tid < nblocks) ? psum[tid] : 0.f;
#pragma unroll
    for (int off = 32; off > 0; off >>= 1)
        v += __shfl_down(v, off, 64);
    if (tid == 0) out[0] = v;   // plain store, no init needed
}

extern "C" void kernel_launch(void* const* d_in, const int* in_sizes, int n_in,
                              void* d_out, int out_size, void* d_ws, size_t ws_size,
                              hipStream_t stream) {
    const float* a     = (const float*)d_in[0];
    const float* b     = (const float*)d_in[1];
    const int*   a_idx = (const int*)d_in[2];
    const int*   b_idx = (const int*)d_in[3];
    float*       out   = (float*)d_out;

    const int N = in_sizes[0] / 3;   // 16384 points in a/b
    const int n = in_sizes[2];       // 8192 samples

    const int a_chunks = n / (BLOCK * NPTS_A);            // 4
    const int b_chunks = n / BPTS;                        // 128
    const int nblocks2 = n / BLOCK;                       // 32

    float* pmin = (float*)d_ws;                           // [b_chunks][n] = 4 MB
    float* psum = pmin + (size_t)b_chunks * n;            // [nblocks2]

    chamfer_min_kernel<<<a_chunks * b_chunks, BLOCK, 0, stream>>>(
        a, b, a_idx, b_idx, pmin, N, n, a_chunks);

    chamfer_colmin_sum_kernel<<<nblocks2, BLOCK, 0, stream>>>(
        a, a_idx, pmin, psum, N, n, b_chunks);

    chamfer_final_kernel<<<1, 64, 0, stream>>>(psum, out, nblocks2);
}

// Round 3
// 75.644 us; speedup vs baseline: 1.4501x; 1.4501x over previous
//
#include <hip/hip_runtime.h>
#include <stdint.h>

// SampleChamfer: out = sum_i min_k ||pa_i - pb_k||^2
// pa_i = a[:, a_idx[i]], pb_k = b[:, b_idx[k]], fp32 scalar out.
//
// d = sq_a[i] + (sq_b[k] - 2*dot(pb_k, pa_i)); min over k; sum over i.
//
// 4 dispatches, no memsets, no atomics:
//  P: gather ONCE -> pa4[i]=(ax,ay,az,||a||^2), pb4[i]=(-2bx,-2by,-2bz,||b||^2).
//     (kills the 64-128x redundant random gathers of rounds 1-2)
//  M: grid 8 a-chunks x 64 b-chunks = 512 blocks (2/CU). 128 b-points in LDS,
//     4 a-points/thread in registers (16 indep VALU ops per broadcast
//     ds_read_b128). Plain store partial min to pmin[bc][i] (2 MB).
//  B: per a-point 64-way min (unroll 8 -> outstanding loads) + pa4[i].w,
//     block-sum -> psum[32].
//  C: one wave sums 32 partials, stores d_out.

#define BLOCK   256
#define NPTS_A  4     // a-points per thread -> 1024 a-points/block, 8 a-chunks
#define BPTS    128   // b-points per block  -> 64 b-chunks; grid = 512

__global__ __launch_bounds__(BLOCK)
void chamfer_pack_kernel(const float* __restrict__ a,
                         const float* __restrict__ b,
                         const int* __restrict__ a_idx,
                         const int* __restrict__ b_idx,
                         float4* __restrict__ pa4,
                         float4* __restrict__ pb4,
                         int N, int n) {
    int i = blockIdx.x * BLOCK + threadIdx.x;
    if (i < n) {
        int ai = a_idx[i];
        float x = a[ai], y = a[N + ai], z = a[2 * N + ai];
        pa4[i] = make_float4(x, y, z, x * x + y * y + z * z);
        int bi = b_idx[i];
        float u = b[bi], v = b[N + bi], w = b[2 * N + bi];
        pb4[i] = make_float4(-2.f * u, -2.f * v, -2.f * w,
                             u * u + v * v + w * w);
    }
}

__global__ __launch_bounds__(BLOCK)
void chamfer_min_kernel(const float4* __restrict__ pa4,
                        const float4* __restrict__ pb4,
                        float* __restrict__ pmin,
                        int n, int a_chunks) {
    __shared__ float4 tile[BPTS];
    const int bid = blockIdx.x;
    const int ac  = bid % a_chunks;
    const int bc  = bid / a_chunks;
    const int tid = threadIdx.x;

    if (tid < BPTS)
        tile[tid] = pb4[bc * BPTS + tid];   // coalesced float4 copy
    __syncthreads();

    float ax[NPTS_A], ay[NPTS_A], az[NPTS_A], mn[NPTS_A];
#pragma unroll
    for (int m = 0; m < NPTS_A; ++m) {
        int i = ac * (BLOCK * NPTS_A) + m * BLOCK + tid;  // coalesced float4
        float4 p = pa4[i];
        ax[m] = p.x; ay[m] = p.y; az[m] = p.z;
        mn[m] = 3.4e38f;
    }

    // 1 broadcast ds_read_b128 per k serves 4 a-points x 4 VALU ops;
    // unroll 4 -> 64 indep ops in flight between LDS waits.
#pragma unroll 4
    for (int k = 0; k < BPTS; ++k) {
        float4 t = tile[k];
#pragma unroll
        for (int m = 0; m < NPTS_A; ++m) {
            float c = fmaf(t.x, ax[m], fmaf(t.y, ay[m], fmaf(t.z, az[m], t.w)));
            mn[m] = fminf(mn[m], c);
        }
    }

#pragma unroll
    for (int m = 0; m < NPTS_A; ++m) {
        int i = ac * (BLOCK * NPTS_A) + m * BLOCK + tid;
        pmin[(size_t)bc * n + i] = mn[m];   // coalesced store
    }
}

__global__ __launch_bounds__(BLOCK)
void chamfer_colmin_sum_kernel(const float4* __restrict__ pa4,
                               const float* __restrict__ pmin,
                               float* __restrict__ psum,
                               int n, int b_chunks) {
    __shared__ float wsum[BLOCK / 64];
    const int tid = threadIdx.x;
    const int i = blockIdx.x * BLOCK + tid;

    float v = 3.4e38f;
#pragma unroll 8
    for (int j = 0; j < b_chunks; ++j)      // coalesced, 8 loads in flight
        v = fminf(v, pmin[(size_t)j * n + i]);

    v += pa4[i].w;                          // ||a_i||^2, packed — no gather

#pragma unroll
    for (int off = 32; off > 0; off >>= 1)
        v += __shfl_down(v, off, 64);
    if ((tid & 63) == 0) wsum[tid >> 6] = v;
    __syncthreads();
    if (tid == 0) {
        float s = 0.f;
#pragma unroll
        for (int w = 0; w < BLOCK / 64; ++w) s += wsum[w];
        psum[blockIdx.x] = s;
    }
}

__global__ __launch_bounds__(64)
void chamfer_final_kernel(const float* __restrict__ psum,
                          float* __restrict__ out, int nblocks) {
    const int tid = threadIdx.x;
    float v = (tid < nblocks) ? psum[tid] : 0.f;
#pragma unroll
    for (int off = 32; off > 0; off >>= 1)
        v += __shfl_down(v, off, 64);
    if (tid == 0) out[0] = v;
}

extern "C" void kernel_launch(void* const* d_in, const int* in_sizes, int n_in,
                              void* d_out, int out_size, void* d_ws, size_t ws_size,
                              hipStream_t stream) {
    const float* a     = (const float*)d_in[0];
    const float* b     = (const float*)d_in[1];
    const int*   a_idx = (const int*)d_in[2];
    const int*   b_idx = (const int*)d_in[3];
    float*       out   = (float*)d_out;

    const int N = in_sizes[0] / 3;   // 16384
    const int n = in_sizes[2];       // 8192

    const int a_chunks = n / (BLOCK * NPTS_A);   // 8
    const int b_chunks = n / BPTS;               // 64
    const int nblocks2 = n / BLOCK;              // 32

    // ws layout: pa4 [n], pb4 [n], pmin [b_chunks*n], psum [nblocks2]
    float4* pa4  = (float4*)d_ws;
    float4* pb4  = pa4 + n;
    float*  pmin = (float*)(pb4 + n);
    float*  psum = pmin + (size_t)b_chunks * n;

    chamfer_pack_kernel<<<(n + BLOCK - 1) / BLOCK, BLOCK, 0, stream>>>(
        a, b, a_idx, b_idx, pa4, pb4, N, n);

    chamfer_min_kernel<<<a_chunks * b_chunks, BLOCK, 0, stream>>>(
        pa4, pb4, pmin, n, a_chunks);

    chamfer_colmin_sum_kernel<<<nblocks2, BLOCK, 0, stream>>>(
        pa4, pmin, psum, n, b_chunks);

    chamfer_final_kernel<<<1, 64, 0, stream>>>(psum, out, nblocks2);
}

// Round 4
// 69.730 us; speedup vs baseline: 1.5731x; 1.0848x over previous
//
#include <hip/hip_runtime.h>
#include <stdint.h>

// SampleChamfer: out = sum_i min_k ||pa_i - pb_k||^2
// pa_i = a[:, a_idx[i]], pb_k = b[:, b_idx[k]], fp32 scalar out.
//
// d = sq_a[i] + (sq_b[k] - 2*dot(pb_k, pa_i)); min over k; sum over i.
//
// 3 dispatches, no memsets:
//  P: gather ONCE -> pa4[i]=(ax,ay,az,||a||^2), pb4[i]=(-2bx,-2by,-2bz,||b||^2);
//     also inits minarr[i]=0xFFFFFFFF (encoded +inf) and zeroes d_out.
//  M: grid 8 a-chunks x 128 b-chunks = 1024 blocks (4/CU). 64 b-points in LDS,
//     4 a-points/thread in registers; combine across b-chunks with
//     fire-and-forget atomicMin on an order-preserving uint encoding
//     (exact & deterministic — integer min is associative).
//  R: 32 blocks decode minarr, add ||a||^2, block-sum, atomicAdd -> d_out.

#define BLOCK   256
#define NPTS_A  4     // a-points per thread -> 1024 a-points/block, 8 a-chunks
#define BPTS    64    // b-points per block  -> 128 b-chunks; grid = 1024

// Order-preserving float -> uint32 (monotone for all floats incl. negatives)
__device__ __forceinline__ unsigned enc_f32(float f) {
    unsigned u = __float_as_uint(f);
    return (u & 0x80000000u) ? ~u : (u | 0x80000000u);
}
__device__ __forceinline__ float dec_f32(unsigned u) {
    return (u & 0x80000000u) ? __uint_as_float(u & 0x7FFFFFFFu)
                             : __uint_as_float(~u);
}

__global__ __launch_bounds__(BLOCK)
void chamfer_pack_kernel(const float* __restrict__ a,
                         const float* __restrict__ b,
                         const int* __restrict__ a_idx,
                         const int* __restrict__ b_idx,
                         float4* __restrict__ pa4,
                         float4* __restrict__ pb4,
                         unsigned* __restrict__ minarr,
                         float* __restrict__ out,
                         int N, int n) {
    int i = blockIdx.x * BLOCK + threadIdx.x;
    if (i < n) {
        int ai = a_idx[i];
        float x = a[ai], y = a[N + ai], z = a[2 * N + ai];
        pa4[i] = make_float4(x, y, z, x * x + y * y + z * z);
        int bi = b_idx[i];
        float u = b[bi], v = b[N + bi], w = b[2 * N + bi];
        pb4[i] = make_float4(-2.f * u, -2.f * v, -2.f * w,
                             u * u + v * v + w * w);
        minarr[i] = 0xFFFFFFFFu;            // encoded +max
    }
    if (i == 0) out[0] = 0.f;               // d_out is poisoned each iter
}

__global__ __launch_bounds__(BLOCK)
void chamfer_min_kernel(const float4* __restrict__ pa4,
                        const float4* __restrict__ pb4,
                        unsigned* __restrict__ minarr,
                        int a_chunks) {
    __shared__ float4 tile[BPTS];
    const int bid = blockIdx.x;
    const int ac  = bid % a_chunks;
    const int bc  = bid / a_chunks;
    const int tid = threadIdx.x;

    if (tid < BPTS)
        tile[tid] = pb4[bc * BPTS + tid];    // coalesced float4 copy
    __syncthreads();

    float ax[NPTS_A], ay[NPTS_A], az[NPTS_A], mn[NPTS_A];
#pragma unroll
    for (int m = 0; m < NPTS_A; ++m) {
        int i = ac * (BLOCK * NPTS_A) + m * BLOCK + tid;  // coalesced float4
        float4 p = pa4[i];
        ax[m] = p.x; ay[m] = p.y; az[m] = p.z;
        mn[m] = 3.4e38f;
    }

    // 1 broadcast ds_read_b128 per k serves 4 a-points x 4 VALU ops;
    // unroll 8 -> many independent ops between LDS waits.
#pragma unroll 8
    for (int k = 0; k < BPTS; ++k) {
        float4 t = tile[k];
#pragma unroll
        for (int m = 0; m < NPTS_A; ++m) {
            float c = fmaf(t.x, ax[m], fmaf(t.y, ay[m], fmaf(t.z, az[m], t.w)));
            mn[m] = fminf(mn[m], c);
        }
    }

    // Fire-and-forget (no return value -> no wait), coalesced across lanes.
#pragma unroll
    for (int m = 0; m < NPTS_A; ++m) {
        int i = ac * (BLOCK * NPTS_A) + m * BLOCK + tid;
        atomicMin(&minarr[i], enc_f32(mn[m]));
    }
}

__global__ __launch_bounds__(BLOCK)
void chamfer_reduce_kernel(const float4* __restrict__ pa4,
                           const unsigned* __restrict__ minarr,
                           float* __restrict__ out) {
    __shared__ float wsum[BLOCK / 64];
    const int tid = threadIdx.x;
    const int i = blockIdx.x * BLOCK + tid;

    float v = dec_f32(minarr[i]) + pa4[i].w;

#pragma unroll
    for (int off = 32; off > 0; off >>= 1)
        v += __shfl_down(v, off, 64);
    if ((tid & 63) == 0) wsum[tid >> 6] = v;
    __syncthreads();
    if (tid == 0) {
        float s = 0.f;
#pragma unroll
        for (int w = 0; w < BLOCK / 64; ++w) s += wsum[w];
        atomicAdd(out, s);                   // out pre-zeroed by pack kernel
    }
}

extern "C" void kernel_launch(void* const* d_in, const int* in_sizes, int n_in,
                              void* d_out, int out_size, void* d_ws, size_t ws_size,
                              hipStream_t stream) {
    const float* a     = (const float*)d_in[0];
    const float* b     = (const float*)d_in[1];
    const int*   a_idx = (const int*)d_in[2];
    const int*   b_idx = (const int*)d_in[3];
    float*       out   = (float*)d_out;

    const int N = in_sizes[0] / 3;   // 16384
    const int n = in_sizes[2];       // 8192

    const int a_chunks = n / (BLOCK * NPTS_A);   // 8
    const int b_chunks = n / BPTS;               // 128

    // ws layout: pa4 [n], pb4 [n], minarr [n]
    float4*   pa4    = (float4*)d_ws;
    float4*   pb4    = pa4 + n;
    unsigned* minarr = (unsigned*)(pb4 + n);

    chamfer_pack_kernel<<<n / BLOCK, BLOCK, 0, stream>>>(
        a, b, a_idx, b_idx, pa4, pb4, minarr, out, N, n);

    chamfer_min_kernel<<<a_chunks * b_chunks, BLOCK, 0, stream>>>(
        pa4, pb4, minarr, a_chunks);

    chamfer_reduce_kernel<<<n / BLOCK, BLOCK, 0, stream>>>(
        pa4, minarr, out);
}